// Round 4
// baseline (60.700 us; speedup 1.0000x reference)
//
#include <hip/hip_runtime.h>

// Problem constants (from reference)
#define C       256      // C_IN == C_OUT
#define KTOP    16.0f
#define NITER   50
#define BATCH   8
#define LENGTH  16384
#define L8      (LENGTH / 8)      // 2048 8-float chunks per row
#define NROWS   (BATCH * C)       // 2048 rows
#define TOTAL8  (NROWS * L8)      // 4,194,304 threads (2 float4 each)

// native 4-float vector (works with __builtin_nontemporal_store, unlike
// HIP's float4 class type)
typedef float f4 __attribute__((ext_vector_type(4)));

// ---------------------------------------------------------------------------
// Wave-wide (64-lane) float sum via DPP — pure VALU, no LDS, no waitcnt.
// ---------------------------------------------------------------------------
__device__ __forceinline__ float wave_sum_dpp(float x) {
    float t;
    t = __int_as_float(__builtin_amdgcn_update_dpp(0, __float_as_int(x), 0x111, 0xf, 0xf, false)); // row_shr:1
    x += t;
    t = __int_as_float(__builtin_amdgcn_update_dpp(0, __float_as_int(x), 0x112, 0xf, 0xf, false)); // row_shr:2
    x += t;
    t = __int_as_float(__builtin_amdgcn_update_dpp(0, __float_as_int(x), 0x114, 0xf, 0xf, false)); // row_shr:4
    x += t;
    t = __int_as_float(__builtin_amdgcn_update_dpp(0, __float_as_int(x), 0x118, 0xf, 0xf, false)); // row_shr:8
    x += t;
    t = __int_as_float(__builtin_amdgcn_update_dpp(0, __float_as_int(x), 0x142, 0xa, 0xf, false)); // row_bcast:15
    x += t;
    t = __int_as_float(__builtin_amdgcn_update_dpp(0, __float_as_int(x), 0x143, 0xc, 0xf, false)); // row_bcast:31
    x += t;
    return __int_as_float(__builtin_amdgcn_readlane(__float_as_int(x), 63));
}

// wave_shr:1 — lane i gets lane i-1's value (shfl_up by 1), pure VALU
__device__ __forceinline__ float dpp_shr1(float x) {
    return __int_as_float(__builtin_amdgcn_update_dpp(0, __float_as_int(x), 0x138, 0xf, 0xf, false));
}
// wave_shl:1 — lane i gets lane i+1's value (shfl_down by 1), pure VALU
__device__ __forceinline__ float dpp_shl1(float x) {
    return __int_as_float(__builtin_amdgcn_update_dpp(0, __float_as_int(x), 0x130, 0xf, 0xf, false));
}

// ---------------------------------------------------------------------------
// Kernel 1: Dykstra sparse-soft-topk on alpha (n=256) with ONE wave (64 lanes,
// 4 elements per lane), then dv[o] = y[0] * V[0,o].
// p = (sum(u)-k)/n is the SAME scalar for all elements -> scalar register.
// ---------------------------------------------------------------------------
__global__ __launch_bounds__(64) void prep_kernel(const float* __restrict__ alpha,
                                                  const float* __restrict__ V,
                                                  float* __restrict__ dv) {
    const int t = threadIdx.x;   // 0..63
    float y[4], q[4];
    float p = 0.0f;
#pragma unroll
    for (int j = 0; j < 4; ++j) {
        y[j] = alpha[t * 4 + j] / 0.01f;   // y0 = s / l
        q[j] = 0.0f;
    }

    for (int it = 0; it < NITER; ++it) {
        float u[4];
        float part = 0.0f;
#pragma unroll
        for (int j = 0; j < 4; ++j) {
            u[j] = y[j] + p;
            part += u[j];
        }
        const float S = wave_sum_dpp(part);                   // sum over all 256
        const float delta = (S - KTOP) * (1.0f / 256.0f);     // (sum(u)-k)/n
        p = delta;                                            // p = u - z (scalar)
#pragma unroll
        for (int j = 0; j < 4; ++j) {
            const float z = u[j] - delta;
            const float v = z + q[j];
            y[j] = fminf(fmaxf(v, 0.0f), 1.0f);               // clip to [0,1]
            q[j] = v - y[j];
        }
    }

    // only alpha_topk[0] matters: diag_vals[o] = y0 * V[0, o]
    const float y0 = __int_as_float(__builtin_amdgcn_readlane(__float_as_int(y[0]), 0));
#pragma unroll
    for (int j = 0; j < 4; ++j) {
        const int o = t * 4 + j;
        dv[o] = y0 * V[o];   // V row 0
    }
}

// ---------------------------------------------------------------------------
// Kernel 2: out[n,o,t] = dv[o]*(x[t-1]+x[t]+x[t+1]) + bias[o], zero-padded.
// 2x float4 per thread (32 B/lane); halos via wave_shr/shl DPP (no LDS);
// waves never straddle rows (2048 chunks/row, multiple of 64). Non-temporal
// stores keep the write stream from evicting the read stream in L2.
// ---------------------------------------------------------------------------
__global__ __launch_bounds__(256) void conv_kernel(const float* __restrict__ x,
                                                   const float* __restrict__ dv,
                                                   const float* __restrict__ bias,
                                                   f4* __restrict__ out4) {
    const int idx = blockIdx.x * 256 + threadIdx.x;   // < TOTAL8
    const int row = idx >> 11;        // / L8
    const int j   = idx & (L8 - 1);   // 8-float chunk within row
    const int o   = row & (C - 1);    // channel

    const float d = dv[o];
    const float b = bias[o];

    const float* __restrict__ xr = x + ((size_t)row << 14);  // row * LENGTH
    const f4* __restrict__ x4r = reinterpret_cast<const f4*>(xr);
    const f4 v0 = x4r[2 * j];
    const f4 v1 = x4r[2 * j + 1];

    // halo elements: x[8j-1] (prev lane's v1.w) and x[8j+8] (next lane's v0.x)
    float pw = dpp_shr1(v1.w);
    float nx = dpp_shl1(v0.x);
    const int lane = threadIdx.x & 63;
    if (lane == 0)  pw = (j > 0)      ? xr[8 * j - 1] : 0.0f;
    if (lane == 63) nx = (j < L8 - 1) ? xr[8 * j + 8] : 0.0f;

    f4 r0, r1;
    r0.x = fmaf(d, pw   + v0.x + v0.y, b);
    r0.y = fmaf(d, v0.x + v0.y + v0.z, b);
    r0.z = fmaf(d, v0.y + v0.z + v0.w, b);
    r0.w = fmaf(d, v0.z + v0.w + v1.x, b);
    r1.x = fmaf(d, v0.w + v1.x + v1.y, b);
    r1.y = fmaf(d, v1.x + v1.y + v1.z, b);
    r1.z = fmaf(d, v1.y + v1.z + v1.w, b);
    r1.w = fmaf(d, v1.z + v1.w + nx,  b);

    __builtin_nontemporal_store(r0, &out4[2 * idx]);
    __builtin_nontemporal_store(r1, &out4[2 * idx + 1]);
}

extern "C" void kernel_launch(void* const* d_in, const int* in_sizes, int n_in,
                              void* d_out, int out_size, void* d_ws, size_t ws_size,
                              hipStream_t stream) {
    const float* x     = (const float*)d_in[0];   // [8, 256, 16384]
    const float* V     = (const float*)d_in[1];   // [256, 256]
    const float* alpha = (const float*)d_in[2];   // [256]
    const float* bias  = (const float*)d_in[3];   // [256]
    float* out = (float*)d_out;                   // [8, 256, 16384]
    float* dv  = (float*)d_ws;                    // 256 floats scratch

    prep_kernel<<<1, 64, 0, stream>>>(alpha, V, dv);
    conv_kernel<<<TOTAL8 / 256, 256, 0, stream>>>(x, dv, bias, (f4*)out);
}

// Round 5
// 49.791 us; speedup vs baseline: 1.2191x; 1.2191x over previous
//
#include <hip/hip_runtime.h>

// Problem constants (from reference)
#define C       256      // C_IN == C_OUT
#define KTOP    16.0f
#define NITER   50
#define BATCH   8
#define LENGTH  16384
#define L4N     (LENGTH / 4)      // 4096 float4 per row
#define NROWS   (BATCH * C)       // 2048 rows
#define TOTAL4  (NROWS * L4N)     // 8,388,608 float4
#define NBLOCKS (TOTAL4 / 512)    // 512 float4 per 256-thread block -> 16384

// native 4-float vector (works with __builtin_nontemporal_store)
typedef float f4 __attribute__((ext_vector_type(4)));

// ---------------------------------------------------------------------------
// Wave-wide (64-lane) float sum via DPP — pure VALU, no LDS, no waitcnt.
// ---------------------------------------------------------------------------
__device__ __forceinline__ float wave_sum_dpp(float x) {
    float t;
    t = __int_as_float(__builtin_amdgcn_update_dpp(0, __float_as_int(x), 0x111, 0xf, 0xf, false)); // row_shr:1
    x += t;
    t = __int_as_float(__builtin_amdgcn_update_dpp(0, __float_as_int(x), 0x112, 0xf, 0xf, false)); // row_shr:2
    x += t;
    t = __int_as_float(__builtin_amdgcn_update_dpp(0, __float_as_int(x), 0x114, 0xf, 0xf, false)); // row_shr:4
    x += t;
    t = __int_as_float(__builtin_amdgcn_update_dpp(0, __float_as_int(x), 0x118, 0xf, 0xf, false)); // row_shr:8
    x += t;
    t = __int_as_float(__builtin_amdgcn_update_dpp(0, __float_as_int(x), 0x142, 0xa, 0xf, false)); // row_bcast:15
    x += t;
    t = __int_as_float(__builtin_amdgcn_update_dpp(0, __float_as_int(x), 0x143, 0xc, 0xf, false)); // row_bcast:31
    x += t;
    return __int_as_float(__builtin_amdgcn_readlane(__float_as_int(x), 63));
}

// wave_shr:1 — lane i gets lane i-1's value (pure VALU)
__device__ __forceinline__ float dpp_shr1(float x) {
    return __int_as_float(__builtin_amdgcn_update_dpp(0, __float_as_int(x), 0x138, 0xf, 0xf, false));
}
// wave_shl:1 — lane i gets lane i+1's value (pure VALU)
__device__ __forceinline__ float dpp_shl1(float x) {
    return __int_as_float(__builtin_amdgcn_update_dpp(0, __float_as_int(x), 0x130, 0xf, 0xf, false));
}
__device__ __forceinline__ float readlane_f(float x, int l) {
    return __int_as_float(__builtin_amdgcn_readlane(__float_as_int(x), l));
}

// ---------------------------------------------------------------------------
// Kernel 1: Dykstra sparse-soft-topk on alpha (n=256) with ONE wave (64 lanes,
// 4 elements per lane), then dv[o] = y[0] * V[0,o].
// p = (sum(u)-k)/n is the SAME scalar for all elements -> scalar register.
// ---------------------------------------------------------------------------
__global__ __launch_bounds__(64) void prep_kernel(const float* __restrict__ alpha,
                                                  const float* __restrict__ V,
                                                  float* __restrict__ dv) {
    const int t = threadIdx.x;   // 0..63
    float y[4], q[4];
    float p = 0.0f;
#pragma unroll
    for (int j = 0; j < 4; ++j) {
        y[j] = alpha[t * 4 + j] / 0.01f;   // y0 = s / l
        q[j] = 0.0f;
    }

    for (int it = 0; it < NITER; ++it) {
        float u[4];
        float part = 0.0f;
#pragma unroll
        for (int j = 0; j < 4; ++j) {
            u[j] = y[j] + p;
            part += u[j];
        }
        const float S = wave_sum_dpp(part);                   // sum over all 256
        const float delta = (S - KTOP) * (1.0f / 256.0f);     // (sum(u)-k)/n
        p = delta;                                            // p = u - z (scalar)
#pragma unroll
        for (int j = 0; j < 4; ++j) {
            const float z = u[j] - delta;
            const float v = z + q[j];
            y[j] = fminf(fmaxf(v, 0.0f), 1.0f);               // clip to [0,1]
            q[j] = v - y[j];
        }
    }

    // only alpha_topk[0] matters: diag_vals[o] = y0 * V[0, o]
    const float y0 = readlane_f(y[0], 0);
#pragma unroll
    for (int j = 0; j < 4; ++j) {
        const int o = t * 4 + j;
        dv[o] = y0 * V[o];   // V row 0
    }
}

// ---------------------------------------------------------------------------
// Kernel 2: out[n,o,t] = dv[o]*(x[t-1]+x[t]+x[t+1]) + bias[o], zero-padded.
// Each wave owns 128 CONSECUTIVE float4: v0 = x4[c*128+lane], v1 = x4[c*128+
// 64+lane] -> every load/store instruction is 64x16B contiguous (full 64B
// lines; no partial-line write amplification). Halos: DPP within a segment,
// v_readlane across the two segments, scalar loads only at lane 0/63 chunk
// edges. dv/bias are block-uniform -> scalar loads. nt stores keep the
// write-once output from evicting L3-resident x.
// ---------------------------------------------------------------------------
__global__ __launch_bounds__(256) void conv_kernel(const float* __restrict__ x,
                                                   const float* __restrict__ dv,
                                                   const float* __restrict__ bias,
                                                   f4* __restrict__ out4) {
    const int lane = threadIdx.x & 63;
    const int wid  = threadIdx.x >> 6;            // wave in block, 0..3
    const int w    = blockIdx.x * 4 + wid;        // global wave id
    const int row  = w >> 5;                      // 32 chunks of 128 f4 per row
    const int c    = w & 31;                      // chunk within row
    const int j0   = c * 128 + lane;              // float4 index within row
    const int j1   = j0 + 64;
    const int o    = row & (C - 1);               // channel (block-uniform)

    const float d = dv[o];
    const float b = bias[o];

    const float* __restrict__ xr = x + ((size_t)row << 14);  // row * LENGTH
    const f4* __restrict__ x4r = reinterpret_cast<const f4*>(xr);
    const f4 v0 = x4r[j0];
    const f4 v1 = x4r[j1];

    // within-segment halos (pure VALU)
    float pw0 = dpp_shr1(v0.w);   // float before v0.x
    float nx0 = dpp_shl1(v0.x);   // float after  v0.w
    float pw1 = dpp_shr1(v1.w);
    float nx1 = dpp_shl1(v1.x);

    // cross-segment halos via SGPR broadcast
    const float segB_first = readlane_f(v1.x, 0);   // x4[c*128+64].x
    const float segA_last  = readlane_f(v0.w, 63);  // x4[c*128+63].w
    if (lane == 63) {
        nx0 = segB_first;
        nx1 = (c < 31) ? xr[4 * j1 + 4] : 0.0f;     // next chunk / row end
    }
    if (lane == 0) {
        pw1 = segA_last;
        pw0 = (c > 0) ? xr[4 * j0 - 1] : 0.0f;      // prev chunk / row start
    }

    f4 r0, r1;
    r0.x = fmaf(d, pw0  + v0.x + v0.y, b);
    r0.y = fmaf(d, v0.x + v0.y + v0.z, b);
    r0.z = fmaf(d, v0.y + v0.z + v0.w, b);
    r0.w = fmaf(d, v0.z + v0.w + nx0,  b);
    r1.x = fmaf(d, pw1  + v1.x + v1.y, b);
    r1.y = fmaf(d, v1.x + v1.y + v1.z, b);
    r1.z = fmaf(d, v1.y + v1.z + v1.w, b);
    r1.w = fmaf(d, v1.z + v1.w + nx1,  b);

    f4* __restrict__ o4r = out4 + ((size_t)row << 12);
    __builtin_nontemporal_store(r0, &o4r[j0]);
    __builtin_nontemporal_store(r1, &o4r[j1]);
}

extern "C" void kernel_launch(void* const* d_in, const int* in_sizes, int n_in,
                              void* d_out, int out_size, void* d_ws, size_t ws_size,
                              hipStream_t stream) {
    const float* x     = (const float*)d_in[0];   // [8, 256, 16384]
    const float* V     = (const float*)d_in[1];   // [256, 256]
    const float* alpha = (const float*)d_in[2];   // [256]
    const float* bias  = (const float*)d_in[3];   // [256]
    float* out = (float*)d_out;                   // [8, 256, 16384]
    float* dv  = (float*)d_ws;                    // 256 floats scratch

    prep_kernel<<<1, 64, 0, stream>>>(alpha, V, dv);
    conv_kernel<<<NBLOCKS, 256, 0, stream>>>(x, dv, bias, (f4*)out);
}